// Round 1
// baseline (1394.557 us; speedup 1.0000x reference)
//
#include <hip/hip_runtime.h>

// Problem constants (see reference): B_=256, nW=128, N1=N2=256, C=256, H=8, hd=32
#define BH_TOTAL 2048       // 256 batch-windows * 8 heads
#define SCALE_Q 0.17677669529663687f   // 32^-0.5

// ---------------------------------------------------------------------------
// Generic fp32 tiled GEMM: out = A(Mx256) @ W(Nx256)^T + bias, with scatter
// MODE 0: Q-proj  -> qh[(b*8+h)*8192 + m1*32 + d], value scaled by SCALE_Q
// MODE 1: KV-proj -> k/v split at n=256, same (b,h,n2,d) layout
// MODE 2: P-proj  -> plain row-major out[m*256+n]
// Tile 64x64, BK=32, 256 threads, 4x4 microtile per thread.
// ---------------------------------------------------------------------------
template<int MODE>
__global__ __launch_bounds__(256)
void gemm_kernel(const float* __restrict__ A, const float* __restrict__ W,
                 const float* __restrict__ bias,
                 float* __restrict__ out0, float* __restrict__ out1)
{
    __shared__ float As[32][68];   // [k][m], pad 68 keeps float4-aligned rows
    __shared__ float Ws[32][68];   // [k][n]

    const int tid = threadIdx.x;
    const int m0 = blockIdx.x * 64;
    const int n0 = blockIdx.y * 64;
    const int tx = tid & 15, ty = tid >> 4;

    float acc[4][4] = {};

    for (int k0 = 0; k0 < 256; k0 += 32) {
        __syncthreads();
        #pragma unroll
        for (int it = 0; it < 2; ++it) {
            int f   = tid + it * 256;     // 0..511
            int row = f >> 3;             // 0..63
            int c4  = f & 7;              // float4 column within BK
            float4 av = *(const float4*)&A[(size_t)(m0 + row) * 256 + k0 + c4 * 4];
            As[c4*4+0][row] = av.x; As[c4*4+1][row] = av.y;
            As[c4*4+2][row] = av.z; As[c4*4+3][row] = av.w;
            float4 wv = *(const float4*)&W[(size_t)(n0 + row) * 256 + k0 + c4 * 4];
            Ws[c4*4+0][row] = wv.x; Ws[c4*4+1][row] = wv.y;
            Ws[c4*4+2][row] = wv.z; Ws[c4*4+3][row] = wv.w;
        }
        __syncthreads();
        #pragma unroll
        for (int k = 0; k < 32; ++k) {
            float4 a4 = *(const float4*)&As[k][ty * 4];
            float4 w4 = *(const float4*)&Ws[k][tx * 4];
            float a_[4] = {a4.x, a4.y, a4.z, a4.w};
            float w_[4] = {w4.x, w4.y, w4.z, w4.w};
            #pragma unroll
            for (int i = 0; i < 4; ++i)
                #pragma unroll
                for (int j = 0; j < 4; ++j)
                    acc[i][j] = fmaf(a_[i], w_[j], acc[i][j]);
        }
    }

    #pragma unroll
    for (int i = 0; i < 4; ++i) {
        int m  = m0 + ty * 4 + i;
        int b  = m >> 8;
        int m1 = m & 255;
        #pragma unroll
        for (int j = 0; j < 4; ++j) {
            int n = n0 + tx * 4 + j;
            float v = acc[i][j] + bias[n];
            if (MODE == 0) {
                out0[(size_t)((b << 3) | (n >> 5)) * 8192 + m1 * 32 + (n & 31)] = v * SCALE_Q;
            } else if (MODE == 1) {
                if (n < 256)
                    out0[(size_t)((b << 3) | (n >> 5)) * 8192 + m1 * 32 + (n & 31)] = v;
                else {
                    int nn = n - 256;
                    out1[(size_t)((b << 3) | (nn >> 5)) * 8192 + m1 * 32 + (nn & 31)] = v;
                }
            } else {
                out0[(size_t)m * 256 + n] = v;
            }
        }
    }
}

// ---------------------------------------------------------------------------
// Attention: one workgroup per (b,h). 4 waves; each wave owns 2 q-rows per
// iteration. K kept transposed in LDS (Kt[d][j]) for j-vectorized QK; V kept
// row-major (Vs[j][d]) for d-parallel PV. Softmax fp32 via wave shuffles.
// bias_table gather + mask add fused into the logits.
// ---------------------------------------------------------------------------
__global__ __launch_bounds__(256)
void attn_kernel(const float* __restrict__ qh, const float* __restrict__ kbuf,
                 const float* __restrict__ vbuf, const float* __restrict__ mask,
                 const float* __restrict__ bias_table,
                 const int* __restrict__ rel_index, float* __restrict__ xbuf)
{
    __shared__ float Kt[32][256];     // Kt[d][j]
    __shared__ float Vs[256][32];     // Vs[j][d]
    __shared__ float prow[4][2][256]; // per-wave softmax rows
    __shared__ float qs[4][2][32];    // per-wave staged q rows

    const int bh   = blockIdx.x;
    const int b    = bh >> 3, h = bh & 7;
    const int tid  = threadIdx.x;
    const int lane = tid & 63, wave = tid >> 6;

    const float* __restrict__ Kg = kbuf + (size_t)bh * 8192;
    const float* __restrict__ Vg = vbuf + (size_t)bh * 8192;
    const float* __restrict__ Qg = qh   + (size_t)bh * 8192;
    const float* __restrict__ Mg = mask + (size_t)(b & 127) * 65536;

    // stage K (transposed) and V
    for (int t = tid; t < 2048; t += 256) {
        int j = t >> 3, c4 = t & 7;
        float4 kk = *(const float4*)&Kg[j * 32 + c4 * 4];
        Kt[c4*4+0][j] = kk.x; Kt[c4*4+1][j] = kk.y;
        Kt[c4*4+2][j] = kk.z; Kt[c4*4+3][j] = kk.w;
        *(float4*)&Vs[j][c4 * 4] = *(const float4*)&Vg[j * 32 + c4 * 4];
    }
    __syncthreads();

    const int j0 = lane * 4;            // this lane's 4 contiguous columns
    const int dd = lane & 31;           // PV: output dim
    const int jh = (lane >> 5) << 7;    // PV: j half (0 or 128)

    for (int rg = 0; rg < 32; ++rg) {
        const int r0 = rg * 8 + wave * 2;
        const int r1 = r0 + 1;

        if (lane < 32) qs[wave][0][lane]      = Qg[r0 * 32 + lane];
        else           qs[wave][1][lane - 32] = Qg[r1 * 32 + (lane - 32)];

        // ---- QK^T for rows r0,r1 (q already carries the 1/sqrt(hd) scale)
        float s0[4] = {0.f, 0.f, 0.f, 0.f};
        float s1[4] = {0.f, 0.f, 0.f, 0.f};
        #pragma unroll
        for (int d = 0; d < 32; ++d) {
            float q0 = qs[wave][0][d];
            float q1 = qs[wave][1][d];
            float4 kd = *(const float4*)&Kt[d][j0];
            s0[0] = fmaf(q0, kd.x, s0[0]); s0[1] = fmaf(q0, kd.y, s0[1]);
            s0[2] = fmaf(q0, kd.z, s0[2]); s0[3] = fmaf(q0, kd.w, s0[3]);
            s1[0] = fmaf(q1, kd.x, s1[0]); s1[1] = fmaf(q1, kd.y, s1[1]);
            s1[2] = fmaf(q1, kd.z, s1[2]); s1[3] = fmaf(q1, kd.w, s1[3]);
        }

        // ---- logits = s + rel-pos bias + shift mask
        int4  ri0 = *(const int4*)&rel_index[r0 * 256 + j0];
        int4  ri1 = *(const int4*)&rel_index[r1 * 256 + j0];
        float4 mk0 = *(const float4*)&Mg[r0 * 256 + j0];
        float4 mk1 = *(const float4*)&Mg[r1 * 256 + j0];
        float l0[4], l1[4];
        l0[0] = s0[0] + bias_table[ri0.x * 8 + h] + mk0.x;
        l0[1] = s0[1] + bias_table[ri0.y * 8 + h] + mk0.y;
        l0[2] = s0[2] + bias_table[ri0.z * 8 + h] + mk0.z;
        l0[3] = s0[3] + bias_table[ri0.w * 8 + h] + mk0.w;
        l1[0] = s1[0] + bias_table[ri1.x * 8 + h] + mk1.x;
        l1[1] = s1[1] + bias_table[ri1.y * 8 + h] + mk1.y;
        l1[2] = s1[2] + bias_table[ri1.z * 8 + h] + mk1.z;
        l1[3] = s1[3] + bias_table[ri1.w * 8 + h] + mk1.w;

        // ---- softmax over 256 (wave-wide, 4 per lane)
        float mx0 = fmaxf(fmaxf(l0[0], l0[1]), fmaxf(l0[2], l0[3]));
        float mx1 = fmaxf(fmaxf(l1[0], l1[1]), fmaxf(l1[2], l1[3]));
        #pragma unroll
        for (int off = 32; off > 0; off >>= 1) {
            mx0 = fmaxf(mx0, __shfl_xor(mx0, off));
            mx1 = fmaxf(mx1, __shfl_xor(mx1, off));
        }
        float e0[4], e1[4];
        float sm0 = 0.f, sm1 = 0.f;
        #pragma unroll
        for (int c = 0; c < 4; ++c) {
            e0[c] = __expf(l0[c] - mx0); sm0 += e0[c];
            e1[c] = __expf(l1[c] - mx1); sm1 += e1[c];
        }
        #pragma unroll
        for (int off = 32; off > 0; off >>= 1) {
            sm0 += __shfl_xor(sm0, off);
            sm1 += __shfl_xor(sm1, off);
        }
        float inv0 = 1.0f / sm0, inv1 = 1.0f / sm1;
        *(float4*)&prow[wave][0][j0] =
            make_float4(e0[0] * inv0, e0[1] * inv0, e0[2] * inv0, e0[3] * inv0);
        *(float4*)&prow[wave][1][j0] =
            make_float4(e1[0] * inv1, e1[1] * inv1, e1[2] * inv1, e1[3] * inv1);

        // ---- PV: lanes 0..31 sum j=0..127 for d=lane, lanes 32..63 the rest
        float a0 = 0.f, a1 = 0.f;
        #pragma unroll 4
        for (int j = 0; j < 128; ++j) {
            float v = Vs[jh + j][dd];
            a0 = fmaf(prow[wave][0][jh + j], v, a0);
            a1 = fmaf(prow[wave][1][jh + j], v, a1);
        }
        a0 += __shfl_xor(a0, 32);
        a1 += __shfl_xor(a1, 32);
        if (lane < 32) {
            xbuf[(size_t)(b * 256 + r0) * 256 + h * 32 + dd] = a0;
            xbuf[(size_t)(b * 256 + r1) * 256 + h * 32 + dd] = a1;
        }
    }
}

// ---------------------------------------------------------------------------
extern "C" void kernel_launch(void* const* d_in, const int* in_sizes, int n_in,
                              void* d_out, int out_size, void* d_ws, size_t ws_size,
                              hipStream_t stream)
{
    const float* q          = (const float*)d_in[0];
    const float* kv         = (const float*)d_in[1];
    const float* mask       = (const float*)d_in[2];
    const float* Wq         = (const float*)d_in[3];
    const float* bq         = (const float*)d_in[4];
    const float* Wkv        = (const float*)d_in[5];
    const float* bkv        = (const float*)d_in[6];
    const float* bias_table = (const float*)d_in[7];
    const float* Wp         = (const float*)d_in[8];
    const float* bp         = (const float*)d_in[9];
    const int*   rel_index  = (const int*)d_in[10];
    float* out = (float*)d_out;

    // workspace: qh | k | v | x, each 65536*256 fp32 = 64 MiB (268 MiB total)
    char* ws = (char*)d_ws;
    float* qh = (float*)(ws);
    float* kb = (float*)(ws + (size_t)67108864);
    float* vb = (float*)(ws + (size_t)134217728);
    float* xb = (float*)(ws + (size_t)201326592);

    dim3 blk(256);
    gemm_kernel<0><<<dim3(1024, 4), blk, 0, stream>>>(q,  Wq,  bq,  qh, nullptr);
    gemm_kernel<1><<<dim3(1024, 8), blk, 0, stream>>>(kv, Wkv, bkv, kb, vb);
    attn_kernel<<<dim3(BH_TOTAL), blk, 0, stream>>>(qh, kb, vb, mask, bias_table,
                                                    rel_index, xb);
    gemm_kernel<2><<<dim3(1024, 4), blk, 0, stream>>>(xb, Wp, bp, out, nullptr);
}

// Round 2
// 1132.473 us; speedup vs baseline: 1.2314x; 1.2314x over previous
//
#include <hip/hip_runtime.h>

// Swin-3D window attention fwd. B_=256 batch-windows, nW=128, N1=N2=256,
// C=256, H=8, hd=32. Threshold ~2.1e-3 (max|ref|*2^-8) licenses bf16 storage.
#define BH_TOTAL 2048
#define SCALE_Q 0.17677669529663687f

typedef unsigned short ushort;
typedef unsigned int uint;
typedef __attribute__((ext_vector_type(8))) short bf16x8;   // 8 bf16 = 4 VGPRs
typedef __attribute__((ext_vector_type(4))) float f32x4;

static __device__ __forceinline__ ushort f2bf(float f) {
    union { float f; uint u; } v; v.f = f;
    uint r = (v.u + 0x7fffu + ((v.u >> 16) & 1u)) >> 16;
    return (ushort)r;
}

// ---------------------------------------------------------------------------
// bias_h[h][r*256+j] = bias_table[rel_index[r*256+j]*8 + h]  (8x65536 fp32)
// ---------------------------------------------------------------------------
__global__ __launch_bounds__(256)
void bias_pre(const float* __restrict__ bias_table, const int* __restrict__ rel_index,
              float* __restrict__ bias_h)
{
    int g  = blockIdx.x * 256 + threadIdx.x;    // 0..524287
    int rj = g & 65535;
    int h  = g >> 16;
    bias_h[g] = bias_table[rel_index[rj] * 8 + h];
}

// ---------------------------------------------------------------------------
// fp32 tiled GEMM: out = A(Mx256) @ W(Nx256)^T + bias, epilogue scatters:
// MODE 0: qh bf16 [(b*8+h)][m1][d], scaled by SCALE_Q
// MODE 1: k bf16 [(bh)][j][d];  v -> TRANSPOSED vt bf16 [(bh)][d][j]
// MODE 2: fp32 row-major out[m*256+n]
// ---------------------------------------------------------------------------
template<int MODE>
__global__ __launch_bounds__(256)
void gemm_kernel(const float* __restrict__ A, const float* __restrict__ W,
                 const float* __restrict__ bias,
                 float* __restrict__ outf, ushort* __restrict__ outh0,
                 ushort* __restrict__ outh1)
{
    __shared__ float As[32][68];
    __shared__ float Ws[32][68];

    const int tid = threadIdx.x;
    const int m0 = blockIdx.x * 64;
    const int n0 = blockIdx.y * 64;
    const int tx = tid & 15, ty = tid >> 4;

    float acc[4][4] = {};

    for (int k0 = 0; k0 < 256; k0 += 32) {
        __syncthreads();
        #pragma unroll
        for (int it = 0; it < 2; ++it) {
            int f   = tid + it * 256;
            int row = f >> 3;
            int c4  = f & 7;
            float4 av = *(const float4*)&A[(size_t)(m0 + row) * 256 + k0 + c4 * 4];
            As[c4*4+0][row] = av.x; As[c4*4+1][row] = av.y;
            As[c4*4+2][row] = av.z; As[c4*4+3][row] = av.w;
            float4 wv = *(const float4*)&W[(size_t)(n0 + row) * 256 + k0 + c4 * 4];
            Ws[c4*4+0][row] = wv.x; Ws[c4*4+1][row] = wv.y;
            Ws[c4*4+2][row] = wv.z; Ws[c4*4+3][row] = wv.w;
        }
        __syncthreads();
        #pragma unroll
        for (int k = 0; k < 32; ++k) {
            float4 a4 = *(const float4*)&As[k][ty * 4];
            float4 w4 = *(const float4*)&Ws[k][tx * 4];
            float a_[4] = {a4.x, a4.y, a4.z, a4.w};
            float w_[4] = {w4.x, w4.y, w4.z, w4.w};
            #pragma unroll
            for (int i = 0; i < 4; ++i)
                #pragma unroll
                for (int j = 0; j < 4; ++j)
                    acc[i][j] = fmaf(a_[i], w_[j], acc[i][j]);
        }
    }

    #pragma unroll
    for (int i = 0; i < 4; ++i) {
        int m  = m0 + ty * 4 + i;
        int b  = m >> 8;
        int m1 = m & 255;
        #pragma unroll
        for (int j = 0; j < 4; ++j) {
            int n = n0 + tx * 4 + j;
            float v = acc[i][j] + bias[n];
            if (MODE == 0) {
                outh0[(size_t)((b << 3) | (n >> 5)) * 8192 + m1 * 32 + (n & 31)]
                    = f2bf(v * SCALE_Q);
            } else if (MODE == 1) {
                if (n < 256)
                    outh0[(size_t)((b << 3) | (n >> 5)) * 8192 + m1 * 32 + (n & 31)]
                        = f2bf(v);
                else {
                    int nn = n - 256;
                    // transposed: vt[(bh)][d][j], row stride 256
                    outh1[(size_t)((b << 3) | (nn >> 5)) * 8192 + (nn & 31) * 256 + m1]
                        = f2bf(v);
                }
            } else {
                outf[(size_t)m * 256 + n] = v;
            }
        }
    }
}

// ---------------------------------------------------------------------------
// MFMA attention. One block (4 waves) per (b,h). 16x16x32 bf16 MFMA.
// QK^T: A=Q rows, B=K rows (B[k][n]=K[n][k]); full hd=32 in one MFMA.
// Softmax fp32 in C/D layout (row=quad*4+reg, col=lane&15) with 16 j-tiles
// in registers; reduce over 16 regs + shfl_xor{1,2,4,8}.
// PV: P round-trips LDS (bf16, A-layout reads), B=Vt rows.
// LDS pads: K stride 40, Vt/P stride 264 -> <=2-way conflicts (free).
// ---------------------------------------------------------------------------
__global__ __launch_bounds__(256)
void attn_mfma(const ushort* __restrict__ qh, const ushort* __restrict__ kb,
               const ushort* __restrict__ vt, const float* __restrict__ mask,
               const float* __restrict__ bias_h, float* __restrict__ xbuf)
{
    __shared__ ushort Ks[256 * 40];       // K[j][d], row stride 40   (20480 B)
    __shared__ ushort Vts[32 * 264];      // Vt[d][j], row stride 264 (16896 B)
    __shared__ ushort Ps[4][16 * 264];    // per-wave P tile          (33792 B)

    const int bh   = blockIdx.x;
    const int b    = bh >> 3, h = bh & 7;
    const int tid  = threadIdx.x;
    const int lane = tid & 63, wave = tid >> 6;
    const int col  = lane & 15;           // n / col within tile
    const int quad = lane >> 4;           // 0..3

    const ushort* __restrict__ Qg = qh + (size_t)bh * 8192;
    const ushort* __restrict__ Kg = kb + (size_t)bh * 8192;
    const ushort* __restrict__ Vg = vt + (size_t)bh * 8192;   // [d][j] stride 256
    const float*  __restrict__ Mg = mask + (size_t)(b & 127) * 65536;
    const float*  __restrict__ Bg = bias_h + (size_t)h * 65536;

    // stage K (row-major, pad 40) and Vt (pad 264)
    for (int t = tid; t < 1024; t += 256) {
        int j = t >> 2, p = t & 3;
        *(bf16x8*)&Ks[j * 40 + p * 8] = *(const bf16x8*)&Kg[j * 32 + p * 8];
    }
    for (int t = tid; t < 1024; t += 256) {
        int d = t >> 5, p = t & 31;
        *(bf16x8*)&Vts[d * 264 + p * 8] = *(const bf16x8*)&Vg[d * 256 + p * 8];
    }
    __syncthreads();

    ushort* __restrict__ Pw = &Ps[wave][0];
    const f32x4 zero = {0.f, 0.f, 0.f, 0.f};

    for (int it = 0; it < 4; ++it) {
        const int qt = wave * 4 + it;
        const int q0 = qt * 16;

        // ---- QK^T: 16 j-tiles, one MFMA each (full K=32)
        bf16x8 aq = *(const bf16x8*)&Qg[(q0 + col) * 32 + quad * 8];
        f32x4 acc[16];
        #pragma unroll
        for (int jt = 0; jt < 16; ++jt) {
            bf16x8 bk = *(const bf16x8*)&Ks[(jt * 16 + col) * 40 + quad * 8];
            acc[jt] = __builtin_amdgcn_mfma_f32_16x16x32_bf16(aq, bk, zero, 0, 0, 0);
        }

        // ---- + rel-pos bias + shift mask (coalesced 64B per 16-lane group)
        #pragma unroll
        for (int jt = 0; jt < 16; ++jt) {
            #pragma unroll
            for (int r = 0; r < 4; ++r) {
                int row = q0 + quad * 4 + r;
                int cidx = row * 256 + jt * 16 + col;
                acc[jt][r] += Mg[cidx] + Bg[cidx];
            }
        }

        // ---- softmax over 256 cols (16 regs x 16 lanes)
        float mx[4], sm[4], inv[4];
        #pragma unroll
        for (int r = 0; r < 4; ++r) {
            float m = acc[0][r];
            #pragma unroll
            for (int jt = 1; jt < 16; ++jt) m = fmaxf(m, acc[jt][r]);
            #pragma unroll
            for (int off = 1; off < 16; off <<= 1) m = fmaxf(m, __shfl_xor(m, off));
            mx[r] = m;
            sm[r] = 0.f;
        }
        #pragma unroll
        for (int jt = 0; jt < 16; ++jt) {
            #pragma unroll
            for (int r = 0; r < 4; ++r) {
                float e = __expf(acc[jt][r] - mx[r]);
                acc[jt][r] = e;
                sm[r] += e;
            }
        }
        #pragma unroll
        for (int r = 0; r < 4; ++r) {
            float s = sm[r];
            #pragma unroll
            for (int off = 1; off < 16; off <<= 1) s += __shfl_xor(s, off);
            inv[r] = 1.0f / s;
        }

        // ---- P -> LDS (bf16), row stride 264
        #pragma unroll
        for (int jt = 0; jt < 16; ++jt) {
            #pragma unroll
            for (int r = 0; r < 4; ++r)
                Pw[(quad * 4 + r) * 264 + jt * 16 + col] = f2bf(acc[jt][r] * inv[r]);
        }
        // wave-internal LDS RAW: lockstep + compiler waitcnt, no barrier needed

        // ---- PV: X(16x32) = P(16x256) @ V(256x32), two d-half tiles
        f32x4 x0 = zero, x1 = zero;
        #pragma unroll
        for (int kc = 0; kc < 8; ++kc) {
            bf16x8 ap  = *(const bf16x8*)&Pw[col * 264 + kc * 32 + quad * 8];
            bf16x8 bv0 = *(const bf16x8*)&Vts[col * 264 + kc * 32 + quad * 8];
            bf16x8 bv1 = *(const bf16x8*)&Vts[(col + 16) * 264 + kc * 32 + quad * 8];
            x0 = __builtin_amdgcn_mfma_f32_16x16x32_bf16(ap, bv0, x0, 0, 0, 0);
            x1 = __builtin_amdgcn_mfma_f32_16x16x32_bf16(ap, bv1, x1, 0, 0, 0);
        }

        // ---- writeback (C/D layout)
        #pragma unroll
        for (int r = 0; r < 4; ++r) {
            int row = q0 + quad * 4 + r;
            size_t base = (size_t)(b * 256 + row) * 256 + h * 32;
            xbuf[base + col]      = x0[r];
            xbuf[base + 16 + col] = x1[r];
        }
    }
}

// ---------------------------------------------------------------------------
extern "C" void kernel_launch(void* const* d_in, const int* in_sizes, int n_in,
                              void* d_out, int out_size, void* d_ws, size_t ws_size,
                              hipStream_t stream)
{
    const float* q          = (const float*)d_in[0];
    const float* kv         = (const float*)d_in[1];
    const float* mask       = (const float*)d_in[2];
    const float* Wq         = (const float*)d_in[3];
    const float* bq         = (const float*)d_in[4];
    const float* Wkv        = (const float*)d_in[5];
    const float* bkv        = (const float*)d_in[6];
    const float* bias_table = (const float*)d_in[7];
    const float* Wp         = (const float*)d_in[8];
    const float* bp         = (const float*)d_in[9];
    const int*   rel_index  = (const int*)d_in[10];
    float* out = (float*)d_out;

    // ws: qh bf16 32MB | k bf16 32MB | vt bf16 32MB | x fp32 64MB | bias_h 2MB
    char* ws = (char*)d_ws;
    ushort* qhb = (ushort*)(ws);
    ushort* kbb = (ushort*)(ws + (size_t)33554432);
    ushort* vtb = (ushort*)(ws + (size_t)67108864);
    float*  xb  = (float*) (ws + (size_t)100663296);
    float*  bh  = (float*) (ws + (size_t)167772160);

    dim3 blk(256);
    bias_pre<<<dim3(2048), blk, 0, stream>>>(bias_table, rel_index, bh);
    gemm_kernel<0><<<dim3(1024, 4), blk, 0, stream>>>(q,  Wq,  bq,  nullptr, qhb, nullptr);
    gemm_kernel<1><<<dim3(1024, 8), blk, 0, stream>>>(kv, Wkv, bkv, nullptr, kbb, vtb);
    attn_mfma<<<dim3(BH_TOTAL), blk, 0, stream>>>(qhb, kbb, vtb, mask, bh, xb);
    gemm_kernel<2><<<dim3(1024, 4), blk, 0, stream>>>(xb, Wp, bp, out, nullptr, nullptr);
}

// Round 3
// 742.778 us; speedup vs baseline: 1.8775x; 1.5246x over previous
//
#include <hip/hip_runtime.h>

// Swin-3D window attention fwd. B_=256 batch-windows, nW=128, N1=N2=256,
// C=256, H=8, hd=32. Threshold ~2.1e-3 (max|ref|*2^-8) licenses bf16 storage.
#define BH_TOTAL 2048
#define SCALE_Q 0.17677669529663687f

typedef unsigned short ushort;
typedef unsigned int uint;
typedef __attribute__((ext_vector_type(8))) short bf16x8;   // 8 bf16 = 4 VGPRs
typedef __attribute__((ext_vector_type(4))) float f32x4;

static __device__ __forceinline__ ushort f2bf(float f) {
    union { float f; uint u; } v; v.f = f;
    uint r = (v.u + 0x7fffu + ((v.u >> 16) & 1u)) >> 16;
    return (ushort)r;
}
static __device__ __forceinline__ float bflo(uint w) {
    union { uint u; float f; } v; v.u = w << 16; return v.f;
}
static __device__ __forceinline__ float bfhi(uint w) {
    union { uint u; float f; } v; v.u = w & 0xffff0000u; return v.f;
}

// ---------------------------------------------------------------------------
// Pre-permute shift mask into MFMA C/D fragment order, bf16:
// maskP[w][row][col][jt] = mask[w][row][jt*16+col].  One block per (w,row).
// ---------------------------------------------------------------------------
__global__ __launch_bounds__(256)
void mask_pre(const float* __restrict__ mask, ushort* __restrict__ maskP)
{
    __shared__ float row[256];
    const int wr = blockIdx.x;            // w*256 + r
    const int tid = threadIdx.x;
    row[tid] = mask[(size_t)wr * 256 + tid];
    __syncthreads();
    // out flat idx within row = col*16 + jt = tid  ->  src j = (tid&15)*16 + (tid>>4)
    maskP[(size_t)wr * 256 + tid] = f2bf(row[(tid & 15) * 16 + (tid >> 4)]);
}

// biasP[h][row][col][jt] = bias_table[rel_index[row*256 + jt*16+col]*8 + h]
__global__ __launch_bounds__(256)
void bias_pre(const float* __restrict__ bias_table, const int* __restrict__ rel_index,
              ushort* __restrict__ biasP)
{
    __shared__ float row[256];
    const int hr = blockIdx.x;            // h*256 + r
    const int h = hr >> 8, r = hr & 255;
    const int tid = threadIdx.x;
    row[tid] = bias_table[rel_index[r * 256 + tid] * 8 + h];
    __syncthreads();
    biasP[(size_t)hr * 256 + tid] = f2bf(row[(tid & 15) * 16 + (tid >> 4)]);
}

// ---------------------------------------------------------------------------
// fp32 tiled GEMM: out = A(Mx256) @ W(Nx256)^T + bias, epilogue scatters:
// MODE 0: qh bf16 [(b*8+h)][m1][d], scaled by SCALE_Q
// MODE 1: k bf16 [(bh)][j][d];  v -> TRANSPOSED vt bf16 [(bh)][d][j]
// MODE 2: fp32 row-major out[m*256+n]
// ---------------------------------------------------------------------------
template<int MODE>
__global__ __launch_bounds__(256)
void gemm_kernel(const float* __restrict__ A, const float* __restrict__ W,
                 const float* __restrict__ bias,
                 float* __restrict__ outf, ushort* __restrict__ outh0,
                 ushort* __restrict__ outh1)
{
    __shared__ float As[32][68];
    __shared__ float Ws[32][68];

    const int tid = threadIdx.x;
    const int m0 = blockIdx.x * 64;
    const int n0 = blockIdx.y * 64;
    const int tx = tid & 15, ty = tid >> 4;

    float acc[4][4] = {};

    for (int k0 = 0; k0 < 256; k0 += 32) {
        __syncthreads();
        #pragma unroll
        for (int it = 0; it < 2; ++it) {
            int f   = tid + it * 256;
            int row = f >> 3;
            int c4  = f & 7;
            float4 av = *(const float4*)&A[(size_t)(m0 + row) * 256 + k0 + c4 * 4];
            As[c4*4+0][row] = av.x; As[c4*4+1][row] = av.y;
            As[c4*4+2][row] = av.z; As[c4*4+3][row] = av.w;
            float4 wv = *(const float4*)&W[(size_t)(n0 + row) * 256 + k0 + c4 * 4];
            Ws[c4*4+0][row] = wv.x; Ws[c4*4+1][row] = wv.y;
            Ws[c4*4+2][row] = wv.z; Ws[c4*4+3][row] = wv.w;
        }
        __syncthreads();
        #pragma unroll
        for (int k = 0; k < 32; ++k) {
            float4 a4 = *(const float4*)&As[k][ty * 4];
            float4 w4 = *(const float4*)&Ws[k][tx * 4];
            float a_[4] = {a4.x, a4.y, a4.z, a4.w};
            float w_[4] = {w4.x, w4.y, w4.z, w4.w};
            #pragma unroll
            for (int i = 0; i < 4; ++i)
                #pragma unroll
                for (int j = 0; j < 4; ++j)
                    acc[i][j] = fmaf(a_[i], w_[j], acc[i][j]);
        }
    }

    #pragma unroll
    for (int i = 0; i < 4; ++i) {
        int m  = m0 + ty * 4 + i;
        int b  = m >> 8;
        int m1 = m & 255;
        #pragma unroll
        for (int j = 0; j < 4; ++j) {
            int n = n0 + tx * 4 + j;
            float v = acc[i][j] + bias[n];
            if (MODE == 0) {
                outh0[(size_t)((b << 3) | (n >> 5)) * 8192 + m1 * 32 + (n & 31)]
                    = f2bf(v * SCALE_Q);
            } else if (MODE == 1) {
                if (n < 256)
                    outh0[(size_t)((b << 3) | (n >> 5)) * 8192 + m1 * 32 + (n & 31)]
                        = f2bf(v);
                else {
                    int nn = n - 256;
                    outh1[(size_t)((b << 3) | (nn >> 5)) * 8192 + (nn & 31) * 256 + m1]
                        = f2bf(v);
                }
            } else {
                outf[(size_t)m * 256 + n] = v;
            }
        }
    }
}

// ---------------------------------------------------------------------------
// MFMA attention. One block (4 waves) per (b,h). 16x16x32 bf16 MFMA.
// Mask/bias come pre-permuted in C/D fragment order (bf16): each lane loads
// its 16 jt values per row as two dwordx4 -> 16 vector loads/iter instead of
// 128 scalar dword loads (the round-2 latency killer).
// Softmax normalization deferred to the output (x *= 1/sum).
// ---------------------------------------------------------------------------
__global__ __launch_bounds__(256)
void attn_mfma(const ushort* __restrict__ qh, const ushort* __restrict__ kb,
               const ushort* __restrict__ vt, const ushort* __restrict__ maskP,
               const ushort* __restrict__ biasP, float* __restrict__ xbuf)
{
    __shared__ ushort Ks[256 * 40];       // K[j][d], row stride 40   (20480 B)
    __shared__ ushort Vts[32 * 264];      // Vt[d][j], row stride 264 (16896 B)
    __shared__ ushort Ps[4][16 * 264];    // per-wave P~ tile         (33792 B)

    const int bh   = blockIdx.x;
    const int b    = bh >> 3, h = bh & 7;
    const int tid  = threadIdx.x;
    const int lane = tid & 63, wave = tid >> 6;
    const int col  = lane & 15;
    const int quad = lane >> 4;

    const ushort* __restrict__ Qg  = qh + (size_t)bh * 8192;
    const ushort* __restrict__ Kg  = kb + (size_t)bh * 8192;
    const ushort* __restrict__ Vg  = vt + (size_t)bh * 8192;   // [d][j] stride 256
    const ushort* __restrict__ MgP = maskP + (size_t)(b & 127) * 65536;
    const ushort* __restrict__ BgP = biasP + (size_t)h * 65536;

    for (int t = tid; t < 1024; t += 256) {
        int j = t >> 2, p = t & 3;
        *(bf16x8*)&Ks[j * 40 + p * 8] = *(const bf16x8*)&Kg[j * 32 + p * 8];
    }
    for (int t = tid; t < 1024; t += 256) {
        int d = t >> 5, p = t & 31;
        *(bf16x8*)&Vts[d * 264 + p * 8] = *(const bf16x8*)&Vg[d * 256 + p * 8];
    }
    __syncthreads();

    ushort* __restrict__ Pw = &Ps[wave][0];
    const f32x4 zero = {0.f, 0.f, 0.f, 0.f};

    for (int it = 0; it < 4; ++it) {
        const int q0 = (wave * 4 + it) * 16;

        // ---- prefetch mask/bias fragments (independent of MFMA -> in flight)
        uint4 mA[4], mB[4], bA[4], bB[4];
        #pragma unroll
        for (int r = 0; r < 4; ++r) {
            const ushort* mp = &MgP[((q0 + quad * 4 + r) * 16 + col) * 16];
            const ushort* bp = &BgP[((q0 + quad * 4 + r) * 16 + col) * 16];
            mA[r] = *(const uint4*)mp;  mB[r] = *(const uint4*)(mp + 8);
            bA[r] = *(const uint4*)bp;  bB[r] = *(const uint4*)(bp + 8);
        }

        // ---- QK^T: 16 j-tiles, one MFMA each (full K=32)
        bf16x8 aq = *(const bf16x8*)&Qg[(q0 + col) * 32 + quad * 8];
        f32x4 acc[16];
        #pragma unroll
        for (int jt = 0; jt < 16; ++jt) {
            bf16x8 bk = *(const bf16x8*)&Ks[(jt * 16 + col) * 40 + quad * 8];
            acc[jt] = __builtin_amdgcn_mfma_f32_16x16x32_bf16(aq, bk, zero, 0, 0, 0);
        }

        // ---- + bias + mask (bf16 fragments, 2 VALU ops per element)
        #pragma unroll
        for (int r = 0; r < 4; ++r) {
            uint mw[8] = {mA[r].x, mA[r].y, mA[r].z, mA[r].w,
                          mB[r].x, mB[r].y, mB[r].z, mB[r].w};
            uint bw[8] = {bA[r].x, bA[r].y, bA[r].z, bA[r].w,
                          bB[r].x, bB[r].y, bB[r].z, bB[r].w};
            #pragma unroll
            for (int jt = 0; jt < 16; ++jt) {
                float mv = (jt & 1) ? bfhi(mw[jt >> 1]) : bflo(mw[jt >> 1]);
                float bv = (jt & 1) ? bfhi(bw[jt >> 1]) : bflo(bw[jt >> 1]);
                acc[jt][r] += mv + bv;
            }
        }

        // ---- softmax stats over 256 cols (16 regs x 16 lanes)
        float mx[4], sm[4], inv[4];
        #pragma unroll
        for (int r = 0; r < 4; ++r) {
            float m = acc[0][r];
            #pragma unroll
            for (int jt = 1; jt < 16; ++jt) m = fmaxf(m, acc[jt][r]);
            #pragma unroll
            for (int off = 1; off < 16; off <<= 1) m = fmaxf(m, __shfl_xor(m, off));
            mx[r] = m;
            sm[r] = 0.f;
        }
        #pragma unroll
        for (int jt = 0; jt < 16; ++jt) {
            #pragma unroll
            for (int r = 0; r < 4; ++r) {
                float e = __expf(acc[jt][r] - mx[r]);
                acc[jt][r] = e;
                sm[r] += e;
            }
        }
        #pragma unroll
        for (int r = 0; r < 4; ++r) {
            float s = sm[r];
            #pragma unroll
            for (int off = 1; off < 16; off <<= 1) s += __shfl_xor(s, off);
            inv[r] = 1.0f / s;
        }

        // ---- unnormalized P~ -> LDS (bf16), row stride 264
        #pragma unroll
        for (int jt = 0; jt < 16; ++jt) {
            #pragma unroll
            for (int r = 0; r < 4; ++r)
                Pw[(quad * 4 + r) * 264 + jt * 16 + col] = f2bf(acc[jt][r]);
        }
        // wave-internal LDS RAW: lockstep + compiler waitcnt, no barrier needed

        // ---- PV: X(16x32) = P~(16x256) @ V(256x32), two d-half tiles
        f32x4 x0 = zero, x1 = zero;
        #pragma unroll
        for (int kc = 0; kc < 8; ++kc) {
            bf16x8 ap  = *(const bf16x8*)&Pw[col * 264 + kc * 32 + quad * 8];
            bf16x8 bv0 = *(const bf16x8*)&Vts[col * 264 + kc * 32 + quad * 8];
            bf16x8 bv1 = *(const bf16x8*)&Vts[(col + 16) * 264 + kc * 32 + quad * 8];
            x0 = __builtin_amdgcn_mfma_f32_16x16x32_bf16(ap, bv0, x0, 0, 0, 0);
            x1 = __builtin_amdgcn_mfma_f32_16x16x32_bf16(ap, bv1, x1, 0, 0, 0);
        }

        // ---- writeback with deferred softmax scale (C/D layout)
        #pragma unroll
        for (int r = 0; r < 4; ++r) {
            int row = q0 + quad * 4 + r;
            size_t base = (size_t)(b * 256 + row) * 256 + h * 32;
            xbuf[base + col]      = x0[r] * inv[r];
            xbuf[base + 16 + col] = x1[r] * inv[r];
        }
    }
}

// ---------------------------------------------------------------------------
extern "C" void kernel_launch(void* const* d_in, const int* in_sizes, int n_in,
                              void* d_out, int out_size, void* d_ws, size_t ws_size,
                              hipStream_t stream)
{
    const float* q          = (const float*)d_in[0];
    const float* kv         = (const float*)d_in[1];
    const float* mask       = (const float*)d_in[2];
    const float* Wq         = (const float*)d_in[3];
    const float* bq         = (const float*)d_in[4];
    const float* Wkv        = (const float*)d_in[5];
    const float* bkv        = (const float*)d_in[6];
    const float* bias_table = (const float*)d_in[7];
    const float* Wp         = (const float*)d_in[8];
    const float* bp         = (const float*)d_in[9];
    const int*   rel_index  = (const int*)d_in[10];
    float* out = (float*)d_out;

    // ws: qh 32MB | k 32MB | vt 32MB | x fp32 64MB | maskP 16MB | biasP 1MB
    char* ws = (char*)d_ws;
    ushort* qhb = (ushort*)(ws);
    ushort* kbb = (ushort*)(ws + (size_t)33554432);
    ushort* vtb = (ushort*)(ws + (size_t)67108864);
    float*  xb  = (float*) (ws + (size_t)100663296);
    ushort* mP  = (ushort*)(ws + (size_t)167772160);
    ushort* bP  = (ushort*)(ws + (size_t)184549376);

    dim3 blk(256);
    mask_pre<<<dim3(32768), blk, 0, stream>>>(mask, mP);
    bias_pre<<<dim3(2048),  blk, 0, stream>>>(bias_table, rel_index, bP);
    gemm_kernel<0><<<dim3(1024, 4), blk, 0, stream>>>(q,  Wq,  bq,  nullptr, qhb, nullptr);
    gemm_kernel<1><<<dim3(1024, 8), blk, 0, stream>>>(kv, Wkv, bkv, nullptr, kbb, vtb);
    attn_mfma<<<dim3(BH_TOTAL), blk, 0, stream>>>(qhb, kbb, vtb, mP, bP, xb);
    gemm_kernel<2><<<dim3(1024, 4), blk, 0, stream>>>(xb, Wp, bp, out, nullptr, nullptr);
}

// Round 4
// 417.276 us; speedup vs baseline: 3.3420x; 1.7801x over previous
//
#include <hip/hip_runtime.h>
#include <type_traits>

// Swin-3D window attention fwd. B_=256, nW=128, N1=N2=256, C=256, H=8, hd=32.
#define BH_TOTAL 2048
#define SCALE_Q 0.17677669529663687f

typedef unsigned short ushort;
typedef unsigned int uint;
typedef __attribute__((ext_vector_type(8))) short bf16x8;   // 8 bf16 = 4 VGPRs
typedef __attribute__((ext_vector_type(4))) ushort u16x4;
typedef __attribute__((ext_vector_type(4))) float f32x4;

static __device__ __forceinline__ ushort f2bf(float f) {      // RNE
    union { float f; uint u; } v; v.f = f;
    uint r = (v.u + 0x7fffu + ((v.u >> 16) & 1u)) >> 16;
    return (ushort)r;
}
static __device__ __forceinline__ ushort bfru(float f) {      // round-half-up (hot path)
    union { float f; uint u; } v; v.f = f;
    return (ushort)((v.u + 0x8000u) >> 16);
}
static __device__ __forceinline__ float bflo(uint w) {
    union { uint u; float f; } v; v.u = w << 16; return v.f;
}
static __device__ __forceinline__ float bfhi(uint w) {
    union { uint u; float f; } v; v.u = w & 0xffff0000u; return v.f;
}

// ---------------------------------------------------------------------------
// maskP[w][row][col][jt] = mask[w][row][jt*16+col]  (bf16, MFMA C/D order)
// ---------------------------------------------------------------------------
__global__ __launch_bounds__(256)
void mask_pre(const float* __restrict__ mask, ushort* __restrict__ maskP)
{
    __shared__ float row[256];
    const int wr = blockIdx.x;
    const int tid = threadIdx.x;
    row[tid] = mask[(size_t)wr * 256 + tid];
    __syncthreads();
    maskP[(size_t)wr * 256 + tid] = f2bf(row[(tid & 15) * 16 + (tid >> 4)]);
}

// biasP[h][row][col][jt] = bias_table[rel_index[row*256 + jt*16+col]*8 + h]
__global__ __launch_bounds__(256)
void bias_pre(const float* __restrict__ bias_table, const int* __restrict__ rel_index,
              ushort* __restrict__ biasP)
{
    __shared__ float row[256];
    const int hr = blockIdx.x;
    const int h = hr >> 8, r = hr & 255;
    const int tid = threadIdx.x;
    row[tid] = bias_table[rel_index[r * 256 + tid] * 8 + h];
    __syncthreads();
    biasP[(size_t)hr * 256 + tid] = f2bf(row[(tid & 15) * 16 + (tid >> 4)]);
}

// ---------------------------------------------------------------------------
// bf16-MFMA GEMM: C(Mx N) = A(Mx256) @ W(Nx256)^T + bias.
// 128x128 tile, BK=64, 4 waves each 64x64 (4x4 of 16x16x32 MFMA).
// A is fp32 (converted in staging) or bf16 (AT=ushort, direct b128 copy).
// Epilogues: MODE 0 qh bf16 scaled; MODE 1 k bf16 / vt bf16 transposed;
// MODE 2 fp32 row-major.
// ---------------------------------------------------------------------------
template<int MODE, typename AT>
__global__ __launch_bounds__(256)
void gemm_mfma(const AT* __restrict__ A, const float* __restrict__ W,
               const float* __restrict__ bias, float* __restrict__ outf,
               ushort* __restrict__ outh0, ushort* __restrict__ outh1)
{
    __shared__ ushort As[128 * 72];   // [m][k], stride 64+8
    __shared__ ushort Bs[128 * 72];   // [n][k]

    const int tid  = threadIdx.x;
    const int m0   = blockIdx.x * 128;
    const int n0   = blockIdx.y * 128;
    const int lane = tid & 63, wave = tid >> 6;
    const int col  = lane & 15, quad = lane >> 4;
    const int wm   = (wave >> 1) * 64, wn = (wave & 1) * 64;

    f32x4 acc[4][4];
    #pragma unroll
    for (int i = 0; i < 4; ++i)
        #pragma unroll
        for (int j = 0; j < 4; ++j)
            acc[i][j] = (f32x4){0.f, 0.f, 0.f, 0.f};

    for (int k0 = 0; k0 < 256; k0 += 64) {
        __syncthreads();
        if constexpr (std::is_same<AT, float>::value) {
            #pragma unroll
            for (int i = 0; i < 8; ++i) {
                int f = tid + 256 * i;            // 0..2047 float4s
                int row = f >> 4, c4 = f & 15;
                float4 av = *(const float4*)&A[(size_t)(m0 + row) * 256 + k0 + c4 * 4];
                u16x4 p = {bfru(av.x), bfru(av.y), bfru(av.z), bfru(av.w)};
                *(u16x4*)&As[row * 72 + c4 * 4] = p;
            }
        } else {
            #pragma unroll
            for (int i = 0; i < 4; ++i) {
                int f = tid + 256 * i;            // 0..1023 bf16x8s
                int row = f >> 3, c8 = f & 7;
                *(bf16x8*)&As[row * 72 + c8 * 8] =
                    *(const bf16x8*)&A[(size_t)(m0 + row) * 256 + k0 + c8 * 8];
            }
        }
        #pragma unroll
        for (int i = 0; i < 8; ++i) {
            int f = tid + 256 * i;
            int row = f >> 4, c4 = f & 15;
            float4 wv = *(const float4*)&W[(size_t)(n0 + row) * 256 + k0 + c4 * 4];
            u16x4 p = {bfru(wv.x), bfru(wv.y), bfru(wv.z), bfru(wv.w)};
            *(u16x4*)&Bs[row * 72 + c4 * 4] = p;
        }
        __syncthreads();
        #pragma unroll
        for (int ks = 0; ks < 64; ks += 32) {
            bf16x8 af[4], bfr[4];
            #pragma unroll
            for (int t = 0; t < 4; ++t) {
                af[t]  = *(const bf16x8*)&As[(wm + t * 16 + col) * 72 + ks + quad * 8];
                bfr[t] = *(const bf16x8*)&Bs[(wn + t * 16 + col) * 72 + ks + quad * 8];
            }
            #pragma unroll
            for (int mt = 0; mt < 4; ++mt)
                #pragma unroll
                for (int nt = 0; nt < 4; ++nt)
                    acc[mt][nt] = __builtin_amdgcn_mfma_f32_16x16x32_bf16(
                        af[mt], bfr[nt], acc[mt][nt], 0, 0, 0);
        }
    }

    // epilogue: m = m0+wm+mt*16+quad*4+r, n = n0+wn+nt*16+col
    #pragma unroll
    for (int mt = 0; mt < 4; ++mt) {
        const int mb = m0 + wm + mt * 16 + quad * 4;
        #pragma unroll
        for (int nt = 0; nt < 4; ++nt) {
            const int n = n0 + wn + nt * 16 + col;
            const float bn = bias[n];
            if (MODE == 1 && n >= 256) {
                // V: 4 row-contiguous vals -> one 8B store, transposed layout
                const int nn = n - 256;
                const int b = mb >> 8, m1 = mb & 255;
                u16x4 p;
                #pragma unroll
                for (int r = 0; r < 4; ++r)
                    p[r] = f2bf(acc[mt][nt][r] + bn);
                *(u16x4*)&outh1[(size_t)((b << 3) | (nn >> 5)) * 8192
                                + (nn & 31) * 256 + m1] = p;
            } else {
                #pragma unroll
                for (int r = 0; r < 4; ++r) {
                    int m = mb + r;
                    int b = m >> 8, m1 = m & 255;
                    float v = acc[mt][nt][r] + bn;
                    if (MODE == 0) {
                        outh0[(size_t)((b << 3) | (n >> 5)) * 8192 + m1 * 32 + (n & 31)]
                            = f2bf(v * SCALE_Q);
                    } else if (MODE == 1) {
                        outh0[(size_t)((b << 3) | (n >> 5)) * 8192 + m1 * 32 + (n & 31)]
                            = f2bf(v);
                    } else {
                        outf[(size_t)m * 256 + n] = v;
                    }
                }
            }
        }
    }
}

// ---------------------------------------------------------------------------
// MFMA attention (unchanged structure from round 3; x now stored bf16).
// ---------------------------------------------------------------------------
__global__ __launch_bounds__(256)
void attn_mfma(const ushort* __restrict__ qh, const ushort* __restrict__ kb,
               const ushort* __restrict__ vt, const ushort* __restrict__ maskP,
               const ushort* __restrict__ biasP, ushort* __restrict__ xbuf)
{
    __shared__ ushort Ks[256 * 40];
    __shared__ ushort Vts[32 * 264];
    __shared__ ushort Ps[4][16 * 264];

    const int bh   = blockIdx.x;
    const int b    = bh >> 3, h = bh & 7;
    const int tid  = threadIdx.x;
    const int lane = tid & 63, wave = tid >> 6;
    const int col  = lane & 15;
    const int quad = lane >> 4;

    const ushort* __restrict__ Qg  = qh + (size_t)bh * 8192;
    const ushort* __restrict__ Kg  = kb + (size_t)bh * 8192;
    const ushort* __restrict__ Vg  = vt + (size_t)bh * 8192;
    const ushort* __restrict__ MgP = maskP + (size_t)(b & 127) * 65536;
    const ushort* __restrict__ BgP = biasP + (size_t)h * 65536;

    for (int t = tid; t < 1024; t += 256) {
        int j = t >> 2, p = t & 3;
        *(bf16x8*)&Ks[j * 40 + p * 8] = *(const bf16x8*)&Kg[j * 32 + p * 8];
    }
    for (int t = tid; t < 1024; t += 256) {
        int d = t >> 5, p = t & 31;
        *(bf16x8*)&Vts[d * 264 + p * 8] = *(const bf16x8*)&Vg[d * 256 + p * 8];
    }
    __syncthreads();

    ushort* __restrict__ Pw = &Ps[wave][0];
    const f32x4 zero = {0.f, 0.f, 0.f, 0.f};

    for (int it = 0; it < 4; ++it) {
        const int q0 = (wave * 4 + it) * 16;

        uint4 mA[4], mB[4], bA[4], bB[4];
        #pragma unroll
        for (int r = 0; r < 4; ++r) {
            const ushort* mp = &MgP[((q0 + quad * 4 + r) * 16 + col) * 16];
            const ushort* bp = &BgP[((q0 + quad * 4 + r) * 16 + col) * 16];
            mA[r] = *(const uint4*)mp;  mB[r] = *(const uint4*)(mp + 8);
            bA[r] = *(const uint4*)bp;  bB[r] = *(const uint4*)(bp + 8);
        }

        bf16x8 aq = *(const bf16x8*)&Qg[(q0 + col) * 32 + quad * 8];
        f32x4 acc[16];
        #pragma unroll
        for (int jt = 0; jt < 16; ++jt) {
            bf16x8 bk = *(const bf16x8*)&Ks[(jt * 16 + col) * 40 + quad * 8];
            acc[jt] = __builtin_amdgcn_mfma_f32_16x16x32_bf16(aq, bk, zero, 0, 0, 0);
        }

        #pragma unroll
        for (int r = 0; r < 4; ++r) {
            uint mw[8] = {mA[r].x, mA[r].y, mA[r].z, mA[r].w,
                          mB[r].x, mB[r].y, mB[r].z, mB[r].w};
            uint bw[8] = {bA[r].x, bA[r].y, bA[r].z, bA[r].w,
                          bB[r].x, bB[r].y, bB[r].z, bB[r].w};
            #pragma unroll
            for (int jt = 0; jt < 16; ++jt) {
                float mv = (jt & 1) ? bfhi(mw[jt >> 1]) : bflo(mw[jt >> 1]);
                float bv = (jt & 1) ? bfhi(bw[jt >> 1]) : bflo(bw[jt >> 1]);
                acc[jt][r] += mv + bv;
            }
        }

        float mx[4], sm[4], inv[4];
        #pragma unroll
        for (int r = 0; r < 4; ++r) {
            float m = acc[0][r];
            #pragma unroll
            for (int jt = 1; jt < 16; ++jt) m = fmaxf(m, acc[jt][r]);
            #pragma unroll
            for (int off = 1; off < 16; off <<= 1) m = fmaxf(m, __shfl_xor(m, off));
            mx[r] = m;
            sm[r] = 0.f;
        }
        #pragma unroll
        for (int jt = 0; jt < 16; ++jt) {
            #pragma unroll
            for (int r = 0; r < 4; ++r) {
                float e = __expf(acc[jt][r] - mx[r]);
                acc[jt][r] = e;
                sm[r] += e;
            }
        }
        #pragma unroll
        for (int r = 0; r < 4; ++r) {
            float s = sm[r];
            #pragma unroll
            for (int off = 1; off < 16; off <<= 1) s += __shfl_xor(s, off);
            inv[r] = 1.0f / s;
        }

        #pragma unroll
        for (int jt = 0; jt < 16; ++jt) {
            #pragma unroll
            for (int r = 0; r < 4; ++r)
                Pw[(quad * 4 + r) * 264 + jt * 16 + col] = f2bf(acc[jt][r]);
        }

        f32x4 x0 = zero, x1 = zero;
        #pragma unroll
        for (int kc = 0; kc < 8; ++kc) {
            bf16x8 ap  = *(const bf16x8*)&Pw[col * 264 + kc * 32 + quad * 8];
            bf16x8 bv0 = *(const bf16x8*)&Vts[col * 264 + kc * 32 + quad * 8];
            bf16x8 bv1 = *(const bf16x8*)&Vts[(col + 16) * 264 + kc * 32 + quad * 8];
            x0 = __builtin_amdgcn_mfma_f32_16x16x32_bf16(ap, bv0, x0, 0, 0, 0);
            x1 = __builtin_amdgcn_mfma_f32_16x16x32_bf16(ap, bv1, x1, 0, 0, 0);
        }

        #pragma unroll
        for (int r = 0; r < 4; ++r) {
            int row = q0 + quad * 4 + r;
            size_t base = (size_t)(b * 256 + row) * 256 + h * 32;
            xbuf[base + col]      = f2bf(x0[r] * inv[r]);
            xbuf[base + 16 + col] = f2bf(x1[r] * inv[r]);
        }
    }
}

// ---------------------------------------------------------------------------
extern "C" void kernel_launch(void* const* d_in, const int* in_sizes, int n_in,
                              void* d_out, int out_size, void* d_ws, size_t ws_size,
                              hipStream_t stream)
{
    const float* q          = (const float*)d_in[0];
    const float* kv         = (const float*)d_in[1];
    const float* mask       = (const float*)d_in[2];
    const float* Wq         = (const float*)d_in[3];
    const float* bq         = (const float*)d_in[4];
    const float* Wkv        = (const float*)d_in[5];
    const float* bkv        = (const float*)d_in[6];
    const float* bias_table = (const float*)d_in[7];
    const float* Wp         = (const float*)d_in[8];
    const float* bp         = (const float*)d_in[9];
    const int*   rel_index  = (const int*)d_in[10];
    float* out = (float*)d_out;

    // ws: qh 32MB | k 32MB | vt 32MB | x bf16 32MB | maskP 16MB | biasP 1MB
    char* ws = (char*)d_ws;
    ushort* qhb = (ushort*)(ws);
    ushort* kbb = (ushort*)(ws + (size_t)33554432);
    ushort* vtb = (ushort*)(ws + (size_t)67108864);
    ushort* xb  = (ushort*)(ws + (size_t)100663296);
    ushort* mP  = (ushort*)(ws + (size_t)134217728);
    ushort* bP  = (ushort*)(ws + (size_t)150994944);

    dim3 blk(256);
    mask_pre<<<dim3(32768), blk, 0, stream>>>(mask, mP);
    bias_pre<<<dim3(2048),  blk, 0, stream>>>(bias_table, rel_index, bP);
    gemm_mfma<0, float ><<<dim3(512, 2), blk, 0, stream>>>(q,  Wq,  bq,  nullptr, qhb, nullptr);
    gemm_mfma<1, float ><<<dim3(512, 4), blk, 0, stream>>>(kv, Wkv, bkv, nullptr, kbb, vtb);
    attn_mfma<<<dim3(BH_TOTAL), blk, 0, stream>>>(qhb, kbb, vtb, mP, bP, xb);
    gemm_mfma<2, ushort><<<dim3(512, 2), blk, 0, stream>>>(xb, Wp, bp, out, nullptr, nullptr);
}